// Round 1
// baseline (491.535 us; speedup 1.0000x reference)
//
#include <hip/hip_runtime.h>
#include <math.h>

#define NFFT   512
#define HOP    256
#define NFREQ  257
#define NMIC   4
#define NEST   4
#define TSTART 120
#define NANG   361

static constexpr double PI_D = 3.14159265358979323846;

// ---------------------------------------------------------------------------
// Kernel 1: windowed DFT for the 4 needed frames x 4 mics x 257 freqs.
// id = f*16 + m*4 + t  ->  Xs[f][m][t]
// window w[n] = sqrt(0.5*(1-cos(2*pi*n/N))) == sin(pi*n/N)
// frame t (global frame TSTART+t) starts at original sample (TSTART+t-1)*HOP
// (center=True pad of NFFT/2=256 cancels one hop; no reflect region touched).
// ---------------------------------------------------------------------------
__global__ void stft_kernel(const float* __restrict__ x,
                            double* __restrict__ xsre,
                            double* __restrict__ xsim) {
    int id = blockIdx.x * blockDim.x + threadIdx.x;
    if (id >= NFREQ * 16) return;
    int f = id >> 4;
    int m = (id >> 2) & 3;
    int t = id & 3;
    long base = ((long)(TSTART + t - 1) * HOP) * NMIC + m;
    double re = 0.0, im = 0.0;
    for (int n = 0; n < NFFT; ++n) {
        double w = sin(PI_D * (double)n / (double)NFFT);
        double v = (double)x[base + (long)n * NMIC] * w;
        int k = (f * n) & (NFFT - 1);          // exact: e^{-2pi i f n/N} has period N
        double ang = -2.0 * PI_D * (double)k / (double)NFFT;
        double ss, cc;
        sincos(ang, &ss, &cc);
        re += v * cc;
        im += v * ss;
    }
    xsre[id] = re;
    xsim[id] = im;
}

// ---------------------------------------------------------------------------
// Kernel 2: per-frequency 4x4 Hermitian covariance -> complex Jacobi eigen ->
// noise projector P = sum over 2 smallest-eigenvalue eigenvectors of v v^H.
// (Projector is invariant to eigenvector phase/basis choice -> matches eigh.)
// ---------------------------------------------------------------------------
__global__ void eig_kernel(const double* __restrict__ xsre,
                           const double* __restrict__ xsim,
                           double* __restrict__ pre,
                           double* __restrict__ pim) {
    int f = blockIdx.x * blockDim.x + threadIdx.x;
    if (f >= NFREQ) return;

    double Xr[4][4], Xi[4][4];                     // [m][t]
    for (int m = 0; m < 4; ++m)
        for (int t = 0; t < 4; ++t) {
            Xr[m][t] = xsre[f * 16 + m * 4 + t];
            Xi[m][t] = xsim[f * 16 + m * 4 + t];
        }

    // R[m][n] = sum_t X[m,t] * conj(X[n,t])   (scale /EST_NUM irrelevant)
    double Ar[4][4], Ai[4][4];
    for (int m = 0; m < 4; ++m)
        for (int n = 0; n < 4; ++n) {
            double rr = 0.0, ii = 0.0;
            for (int t = 0; t < 4; ++t) {
                rr += Xr[m][t] * Xr[n][t] + Xi[m][t] * Xi[n][t];
                ii += Xi[m][t] * Xr[n][t] - Xr[m][t] * Xi[n][t];
            }
            Ar[m][n] = rr;
            Ai[m][n] = ii;
        }

    double Vr[4][4] = {{1,0,0,0},{0,1,0,0},{0,0,1,0},{0,0,0,1}};
    double Vi[4][4] = {{0,0,0,0},{0,0,0,0},{0,0,0,0},{0,0,0,0}};

    for (int sweep = 0; sweep < 12; ++sweep) {
        for (int p = 0; p < 3; ++p)
            for (int q = p + 1; q < 4; ++q) {
                double ar = Ar[p][q], ai = Ai[p][q];
                double rmag = sqrt(ar * ar + ai * ai);
                if (rmag < 1e-280) continue;
                double er = ar / rmag, ei = ai / rmag;   // e^{i alpha}
                double tau = (Ar[q][q] - Ar[p][p]) / (2.0 * rmag);
                double t_ = (tau >= 0.0 ? 1.0 : -1.0) /
                            (fabs(tau) + sqrt(1.0 + tau * tau));
                double c = 1.0 / sqrt(1.0 + t_ * t_);
                double s = t_ * c;
                // J: J_pp=c, J_pq = s e^{ia}, J_qp = -s e^{-ia}, J_qq = c
                // A <- A J   (columns)
                for (int k = 0; k < 4; ++k) {
                    double apr = Ar[k][p], api = Ai[k][p];
                    double aqr = Ar[k][q], aqi = Ai[k][q];
                    double tr = er * aqr + ei * aqi;      // Re(e^{-ia} aq)
                    double ti = er * aqi - ei * aqr;      // Im(e^{-ia} aq)
                    Ar[k][p] = c * apr - s * tr;
                    Ai[k][p] = c * api - s * ti;
                    double ur = er * apr - ei * api;      // Re(e^{+ia} ap)
                    double ui = er * api + ei * apr;      // Im(e^{+ia} ap)
                    Ar[k][q] = s * ur + c * aqr;
                    Ai[k][q] = s * ui + c * aqi;
                }
                // A <- J^H A   (rows)
                for (int k = 0; k < 4; ++k) {
                    double apr = Ar[p][k], api = Ai[p][k];
                    double aqr = Ar[q][k], aqi = Ai[q][k];
                    double tr = er * aqr - ei * aqi;      // Re(e^{+ia} aq)
                    double ti = er * aqi + ei * aqr;
                    Ar[p][k] = c * apr - s * tr;
                    Ai[p][k] = c * api - s * ti;
                    double ur = er * apr + ei * api;      // Re(e^{-ia} ap)
                    double ui = er * api - ei * apr;
                    Ar[q][k] = s * ur + c * aqr;
                    Ai[q][k] = s * ui + c * aqi;
                }
                // V <- V J   (columns, same as A column update)
                for (int k = 0; k < 4; ++k) {
                    double apr = Vr[k][p], api = Vi[k][p];
                    double aqr = Vr[k][q], aqi = Vi[k][q];
                    double tr = er * aqr + ei * aqi;
                    double ti = er * aqi - ei * aqr;
                    Vr[k][p] = c * apr - s * tr;
                    Vi[k][p] = c * api - s * ti;
                    double ur = er * apr - ei * api;
                    double ui = er * api + ei * apr;
                    Vr[k][q] = s * ur + c * aqr;
                    Vi[k][q] = s * ui + c * aqi;
                }
            }
    }

    double d[4] = {Ar[0][0], Ar[1][1], Ar[2][2], Ar[3][3]};
    int ord[4] = {0, 1, 2, 3};
    for (int i = 0; i < 3; ++i)
        for (int j = 0; j < 3 - i; ++j)
            if (d[ord[j]] > d[ord[j + 1]]) {
                int tmp = ord[j]; ord[j] = ord[j + 1]; ord[j + 1] = tmp;
            }
    // noise subspace = 2 smallest eigenvalues: ord[0], ord[1]
    for (int m = 0; m < 4; ++m)
        for (int n = 0; n < 4; ++n) {
            double rr = 0.0, ii = 0.0;
            for (int jj = 0; jj < 2; ++jj) {
                int j = ord[jj];
                rr += Vr[m][j] * Vr[n][j] + Vi[m][j] * Vi[n][j];
                ii += Vi[m][j] * Vr[n][j] - Vr[m][j] * Vi[n][j];
            }
            pre[f * 16 + m * 4 + n] = rr;
            pim[f * 16 + m * 4 + n] = ii;
        }
}

// ---------------------------------------------------------------------------
// Kernel 3: MUSIC spectrum. One block per angle, one thread per frequency.
// val[a,f] = sum_{mn} s_m conj(s_n) P_mn
//          = tr(P) + 2*sum_{m<n} [cos(phi d) Re P_mn - sin(phi d) Im P_mn],
// d = n - m, s_m = exp(-i phi m), phi = 2 pi D/C sin(theta) f_analog.
// ---------------------------------------------------------------------------
__global__ void music_kernel(const double* __restrict__ pre,
                             const double* __restrict__ pim,
                             float* __restrict__ out) {
    int a = blockIdx.x;
    int f = threadIdx.x;
    double r = 0.0;
    if (f < NFREQ) {
        double theta = (-90.0 + 0.5 * (double)a) * PI_D / 180.0;
        double freq = 31.25 * (double)f;          // FS/2 / 256 = 31.25 Hz
        double phi = 2.0 * PI_D * 0.04 / 343.0 * sin(theta) * freq;
        const double* Pr = pre + f * 16;
        const double* Pi = pim + f * 16;
        double s1, c1, s2, c2, s3, c3;
        sincos(phi, &s1, &c1);
        sincos(2.0 * phi, &s2, &c2);
        sincos(3.0 * phi, &s3, &c3);
        double val = Pr[0] + Pr[5] + Pr[10] + Pr[15]
            + 2.0 * ( c1 * (Pr[1] + Pr[6] + Pr[11]) - s1 * (Pi[1] + Pi[6] + Pi[11])
                    + c2 * (Pr[2] + Pr[7])          - s2 * (Pi[2] + Pi[7])
                    + c3 * Pr[3]                    - s3 * Pi[3] );
        r = 1.0 / (val + 1e-8);
    }
    __shared__ double sm[512];
    sm[threadIdx.x] = r;
    __syncthreads();
    for (int st = 256; st > 0; st >>= 1) {
        if (threadIdx.x < st) sm[threadIdx.x] += sm[threadIdx.x + st];
        __syncthreads();
    }
    if (threadIdx.x == 0) out[a] = (float)(sm[0] / (double)NFREQ);
}

extern "C" void kernel_launch(void* const* d_in, const int* in_sizes, int n_in,
                              void* d_out, int out_size, void* d_ws, size_t ws_size,
                              hipStream_t stream) {
    const float* x = (const float*)d_in[0];
    float* out = (float*)d_out;
    double* ws = (double*)d_ws;
    double* xsre = ws;                 // 257*16 = 4112 doubles
    double* xsim = ws + 4112;
    double* pre  = ws + 2 * 4112;
    double* pim  = ws + 3 * 4112;      // total 131584 bytes

    stft_kernel<<<(NFREQ * 16 + 255) / 256, 256, 0, stream>>>(x, xsre, xsim);
    eig_kernel<<<(NFREQ + 63) / 64, 64, 0, stream>>>(xsre, xsim, pre, pim);
    music_kernel<<<NANG, 512, 0, stream>>>(pre, pim, out);
}

// Round 2
// 168.807 us; speedup vs baseline: 2.9118x; 2.9118x over previous
//
#include <hip/hip_runtime.h>
#include <math.h>

#define NFFT   512
#define HOP    256
#define NFREQ  257
#define NMIC   4
#define NEST   4
#define TSTART 120
#define NANG   361

static constexpr double PI_D = 3.14159265358979323846;

// ---------------------------------------------------------------------------
// Kernel 1: windowed DFT, one block per (m,t), one thread per frequency.
// LDS: windowed signal v[512] + sine table s[j]=sin(pi*j/512), j=0..1023.
// cos(2pi k/512) = s[(2k+256)&1023], sin(2pi k/512) = s[(2k)&1023].
// Table arguments are bit-identical to calling sincos directly.
// ---------------------------------------------------------------------------
__global__ void stft_kernel(const float* __restrict__ x,
                            double* __restrict__ xsre,
                            double* __restrict__ xsim) {
    int m = blockIdx.x >> 2;
    int t = blockIdx.x & 3;
    int tid = threadIdx.x;                 // 512 threads

    __shared__ double v[NFFT];
    __shared__ double stab[1024];

    // build sine table: 2 entries per thread
    stab[tid]       = sin(PI_D * (double)tid / 512.0);
    stab[tid + 512] = sin(PI_D * (double)(tid + 512) / 512.0);

    // windowed frame: frame TSTART+t starts at sample (TSTART+t-1)*HOP
    long base = ((long)(TSTART + t - 1) * HOP) * NMIC + m;
    v[tid] = (double)x[base + (long)tid * NMIC] *
             sin(PI_D * (double)tid / (double)NFFT);
    __syncthreads();

    int f = tid;
    if (f >= NFREQ) return;
    double re = 0.0, im = 0.0;
    for (int n = 0; n < NFFT; ++n) {
        double vn = v[n];
        int k = (f * n) & (NFFT - 1);
        re += vn * stab[(2 * k + 256) & 1023];   // cos
        im -= vn * stab[(2 * k) & 1023];         // sin
    }
    int id = f * 16 + m * 4 + t;
    xsre[id] = re;
    xsim[id] = im;
}

// ---------------------------------------------------------------------------
// Kernel 2: per-frequency 4x4 Hermitian covariance -> complex Jacobi ->
// noise projector. ALL array indexing is compile-time static (registers);
// eigenvalue selection is branchless rank-based (no sort, no runtime index).
// ---------------------------------------------------------------------------
__global__ void eig_kernel(const double* __restrict__ xsre,
                           const double* __restrict__ xsim,
                           double* __restrict__ pre,
                           double* __restrict__ pim) {
    int f = blockIdx.x * blockDim.x + threadIdx.x;
    if (f >= NFREQ) return;

    double Xr[4][4], Xi[4][4];                     // [m][t]
#pragma unroll
    for (int m = 0; m < 4; ++m)
#pragma unroll
        for (int t = 0; t < 4; ++t) {
            Xr[m][t] = xsre[f * 16 + m * 4 + t];
            Xi[m][t] = xsim[f * 16 + m * 4 + t];
        }

    double Ar[4][4], Ai[4][4];
#pragma unroll
    for (int m = 0; m < 4; ++m)
#pragma unroll
        for (int n = 0; n < 4; ++n) {
            double rr = 0.0, ii = 0.0;
#pragma unroll
            for (int t = 0; t < 4; ++t) {
                rr += Xr[m][t] * Xr[n][t] + Xi[m][t] * Xi[n][t];
                ii += Xi[m][t] * Xr[n][t] - Xr[m][t] * Xi[n][t];
            }
            Ar[m][n] = rr;
            Ai[m][n] = ii;
        }

    double Vr[4][4] = {{1,0,0,0},{0,1,0,0},{0,0,1,0},{0,0,0,1}};
    double Vi[4][4] = {{0,0,0,0},{0,0,0,0},{0,0,0,0},{0,0,0,0}};

    for (int sweep = 0; sweep < 8; ++sweep) {
#pragma unroll
        for (int p = 0; p < 3; ++p)
#pragma unroll
            for (int q = p + 1; q < 4; ++q) {
                double ar = Ar[p][q], ai = Ai[p][q];
                double rmag = sqrt(ar * ar + ai * ai);
                if (rmag < 1e-280) continue;
                double inv = 1.0 / rmag;
                double er = ar * inv, ei = ai * inv;     // e^{i alpha}
                double tau = (Ar[q][q] - Ar[p][p]) * (0.5 * inv);
                double t_ = (tau >= 0.0 ? 1.0 : -1.0) /
                            (fabs(tau) + sqrt(1.0 + tau * tau));
                double c = 1.0 / sqrt(1.0 + t_ * t_);
                double s = t_ * c;
                // A <- A J (columns)
#pragma unroll
                for (int k = 0; k < 4; ++k) {
                    double apr = Ar[k][p], api = Ai[k][p];
                    double aqr = Ar[k][q], aqi = Ai[k][q];
                    double tr = er * aqr + ei * aqi;
                    double ti = er * aqi - ei * aqr;
                    Ar[k][p] = c * apr - s * tr;
                    Ai[k][p] = c * api - s * ti;
                    double ur = er * apr - ei * api;
                    double ui = er * api + ei * apr;
                    Ar[k][q] = s * ur + c * aqr;
                    Ai[k][q] = s * ui + c * aqi;
                }
                // A <- J^H A (rows)
#pragma unroll
                for (int k = 0; k < 4; ++k) {
                    double apr = Ar[p][k], api = Ai[p][k];
                    double aqr = Ar[q][k], aqi = Ai[q][k];
                    double tr = er * aqr - ei * aqi;
                    double ti = er * aqi + ei * aqr;
                    Ar[p][k] = c * apr - s * tr;
                    Ai[p][k] = c * api - s * ti;
                    double ur = er * apr + ei * api;
                    double ui = er * api - ei * apr;
                    Ar[q][k] = s * ur + c * aqr;
                    Ai[q][k] = s * ui + c * aqi;
                }
                // V <- V J (columns)
#pragma unroll
                for (int k = 0; k < 4; ++k) {
                    double apr = Vr[k][p], api = Vi[k][p];
                    double aqr = Vr[k][q], aqi = Vi[k][q];
                    double tr = er * aqr + ei * aqi;
                    double ti = er * aqi - ei * aqr;
                    Vr[k][p] = c * apr - s * tr;
                    Vi[k][p] = c * api - s * ti;
                    double ur = er * apr - ei * api;
                    double ui = er * api + ei * apr;
                    Vr[k][q] = s * ur + c * aqr;
                    Vi[k][q] = s * ui + c * aqi;
                }
            }
    }

    // branchless selection of the 2 smallest eigenvalues (static indexing only)
    double dd[4] = {Ar[0][0], Ar[1][1], Ar[2][2], Ar[3][3]};
    double w[4];
#pragma unroll
    for (int j = 0; j < 4; ++j) {
        int rank = 0;
#pragma unroll
        for (int k = 0; k < 4; ++k) {
            if (k == j) continue;
            bool less = (dd[k] < dd[j]) || (dd[k] == dd[j] && k < j);
            rank += less ? 1 : 0;
        }
        w[j] = (rank < 2) ? 1.0 : 0.0;
    }

#pragma unroll
    for (int m = 0; m < 4; ++m)
#pragma unroll
        for (int n = 0; n < 4; ++n) {
            double rr = 0.0, ii = 0.0;
#pragma unroll
            for (int j = 0; j < 4; ++j) {
                rr += w[j] * (Vr[m][j] * Vr[n][j] + Vi[m][j] * Vi[n][j]);
                ii += w[j] * (Vi[m][j] * Vr[n][j] - Vr[m][j] * Vi[n][j]);
            }
            pre[f * 16 + m * 4 + n] = rr;
            pim[f * 16 + m * 4 + n] = ii;
        }
}

// ---------------------------------------------------------------------------
// Kernel 3: MUSIC spectrum, one block per angle, one thread per frequency.
// One fp64 sincos; 2phi/3phi via exact angle-addition identities.
// ---------------------------------------------------------------------------
__global__ void music_kernel(const double* __restrict__ pre,
                             const double* __restrict__ pim,
                             float* __restrict__ out) {
    int a = blockIdx.x;
    int f = threadIdx.x;
    double r = 0.0;
    if (f < NFREQ) {
        double theta = (-90.0 + 0.5 * (double)a) * PI_D / 180.0;
        double freq = 31.25 * (double)f;
        double phi = 2.0 * PI_D * 0.04 / 343.0 * sin(theta) * freq;
        const double* Pr = pre + f * 16;
        const double* Pi = pim + f * 16;
        double s1, c1;
        sincos(phi, &s1, &c1);
        double c2 = c1 * c1 - s1 * s1;
        double s2 = 2.0 * s1 * c1;
        double c3 = c1 * c2 - s1 * s2;
        double s3 = s1 * c2 + c1 * s2;
        double val = Pr[0] + Pr[5] + Pr[10] + Pr[15]
            + 2.0 * ( c1 * (Pr[1] + Pr[6] + Pr[11]) - s1 * (Pi[1] + Pi[6] + Pi[11])
                    + c2 * (Pr[2] + Pr[7])          - s2 * (Pi[2] + Pi[7])
                    + c3 * Pr[3]                    - s3 * Pi[3] );
        r = 1.0 / (val + 1e-8);
    }
    __shared__ double sm[512];
    sm[threadIdx.x] = r;
    __syncthreads();
    for (int st = 256; st > 0; st >>= 1) {
        if (threadIdx.x < st) sm[threadIdx.x] += sm[threadIdx.x + st];
        __syncthreads();
    }
    if (threadIdx.x == 0) out[a] = (float)(sm[0] / (double)NFREQ);
}

extern "C" void kernel_launch(void* const* d_in, const int* in_sizes, int n_in,
                              void* d_out, int out_size, void* d_ws, size_t ws_size,
                              hipStream_t stream) {
    const float* x = (const float*)d_in[0];
    float* out = (float*)d_out;
    double* ws = (double*)d_ws;
    double* xsre = ws;                 // 257*16 = 4112 doubles
    double* xsim = ws + 4112;
    double* pre  = ws + 2 * 4112;
    double* pim  = ws + 3 * 4112;      // total 131584 bytes

    stft_kernel<<<16, 512, 0, stream>>>(x, xsre, xsim);
    eig_kernel<<<(NFREQ + 63) / 64, 64, 0, stream>>>(xsre, xsim, pre, pim);
    music_kernel<<<NANG, 512, 0, stream>>>(pre, pim, out);
}

// Round 3
// 115.801 us; speedup vs baseline: 4.2447x; 1.4577x over previous
//
#include <hip/hip_runtime.h>
#include <math.h>

#define NFFT   512
#define HOP    256
#define NFREQ  257
#define NMIC   4
#define NEST   4
#define TSTART 120
#define NANG   361

static constexpr double PI_D = 3.14159265358979323846;
static constexpr float  PI_F = 3.14159265358979323846f;

// ---------------------------------------------------------------------------
// Kernel 1: windowed DFT, fp32 inner loop, 4-way n-chunk split.
// grid = 64 blocks: b = chunk*16 + m*4 + t ; 512 threads (thread = frequency).
// LDS: cos/sin tables (512 fp32 each) + 128-sample windowed chunk.
// Partial sums (float) go to ws; eig_kernel combines the 4 chunks.
// ---------------------------------------------------------------------------
__global__ __launch_bounds__(512)
void stft_kernel(const float* __restrict__ x,
                 float* __restrict__ part_re,
                 float* __restrict__ part_im) {
    int b = blockIdx.x;
    int chunk = b >> 4;
    int m = (b >> 2) & 3;
    int t = b & 3;
    int tid = threadIdx.x;

    __shared__ float ct[512];
    __shared__ float st[512];
    __shared__ float v[128];

    {   // twiddle tables: angle = 2*pi*k/512
        float ang = (2.0f * PI_F / 512.0f) * (float)tid;
        float s, c;
        sincosf(ang, &s, &c);
        ct[tid] = c;
        st[tid] = s;
    }
    if (tid < 128) {
        int n = chunk * 128 + tid;
        long base = ((long)(TSTART + t - 1) * HOP) * NMIC + m;
        v[tid] = x[base + (long)n * NMIC] * sinf(PI_F * (float)n / 512.0f);
    }
    __syncthreads();

    int f = tid;
    if (f >= NFREQ) return;
    int n0 = chunk * 128;
    int k = (f * n0) & 511;
    float re = 0.0f, im = 0.0f;
#pragma unroll 4
    for (int j = 0; j < 128; ++j) {
        float vn = v[j];
        re += vn * ct[k];
        im -= vn * st[k];
        k = (k + f) & 511;
    }
    int id = f * 16 + m * 4 + t;
    part_re[chunk * 4112 + id] = re;
    part_im[chunk * 4112 + id] = im;
}

// ---------------------------------------------------------------------------
// Kernel 2: combine partials -> 4x4 covariance -> complex Jacobi (6 sweeps) ->
// noise projector. __launch_bounds__(64) so ~200 VGPRs are available and the
// A/V matrices stay fully in registers (round-2 spilled at VGPR cap 64).
// ---------------------------------------------------------------------------
__global__ __launch_bounds__(64)
void eig_kernel(const float* __restrict__ part_re,
                const float* __restrict__ part_im,
                double* __restrict__ pre,
                double* __restrict__ pim) {
    int f = blockIdx.x * blockDim.x + threadIdx.x;
    if (f >= NFREQ) return;

    double Xr[4][4], Xi[4][4];                     // [m][t]
#pragma unroll
    for (int m = 0; m < 4; ++m)
#pragma unroll
        for (int t = 0; t < 4; ++t) {
            int id = f * 16 + m * 4 + t;
            Xr[m][t] = (double)part_re[id] + (double)part_re[4112 + id]
                     + (double)part_re[2 * 4112 + id] + (double)part_re[3 * 4112 + id];
            Xi[m][t] = (double)part_im[id] + (double)part_im[4112 + id]
                     + (double)part_im[2 * 4112 + id] + (double)part_im[3 * 4112 + id];
        }

    double Ar[4][4], Ai[4][4];
#pragma unroll
    for (int m = 0; m < 4; ++m)
#pragma unroll
        for (int n = 0; n < 4; ++n) {
            double rr = 0.0, ii = 0.0;
#pragma unroll
            for (int t = 0; t < 4; ++t) {
                rr += Xr[m][t] * Xr[n][t] + Xi[m][t] * Xi[n][t];
                ii += Xi[m][t] * Xr[n][t] - Xr[m][t] * Xi[n][t];
            }
            Ar[m][n] = rr;
            Ai[m][n] = ii;
        }

    double Vr[4][4] = {{1,0,0,0},{0,1,0,0},{0,0,1,0},{0,0,0,1}};
    double Vi[4][4] = {{0,0,0,0},{0,0,0,0},{0,0,0,0},{0,0,0,0}};

    for (int sweep = 0; sweep < 6; ++sweep) {
#pragma unroll
        for (int p = 0; p < 3; ++p)
#pragma unroll
            for (int q = p + 1; q < 4; ++q) {
                double ar = Ar[p][q], ai = Ai[p][q];
                double rmag = sqrt(ar * ar + ai * ai);
                if (rmag < 1e-280) continue;
                double inv = 1.0 / rmag;
                double er = ar * inv, ei = ai * inv;     // e^{i alpha}
                double tau = (Ar[q][q] - Ar[p][p]) * (0.5 * inv);
                double t_ = (tau >= 0.0 ? 1.0 : -1.0) /
                            (fabs(tau) + sqrt(1.0 + tau * tau));
                double c = 1.0 / sqrt(1.0 + t_ * t_);
                double s = t_ * c;
                // A <- A J (columns)
#pragma unroll
                for (int k = 0; k < 4; ++k) {
                    double apr = Ar[k][p], api = Ai[k][p];
                    double aqr = Ar[k][q], aqi = Ai[k][q];
                    double tr = er * aqr + ei * aqi;
                    double ti = er * aqi - ei * aqr;
                    Ar[k][p] = c * apr - s * tr;
                    Ai[k][p] = c * api - s * ti;
                    double ur = er * apr - ei * api;
                    double ui = er * api + ei * apr;
                    Ar[k][q] = s * ur + c * aqr;
                    Ai[k][q] = s * ui + c * aqi;
                }
                // A <- J^H A (rows)
#pragma unroll
                for (int k = 0; k < 4; ++k) {
                    double apr = Ar[p][k], api = Ai[p][k];
                    double aqr = Ar[q][k], aqi = Ai[q][k];
                    double tr = er * aqr - ei * aqi;
                    double ti = er * aqi + ei * aqr;
                    Ar[p][k] = c * apr - s * tr;
                    Ai[p][k] = c * api - s * ti;
                    double ur = er * apr + ei * api;
                    double ui = er * api - ei * apr;
                    Ar[q][k] = s * ur + c * aqr;
                    Ai[q][k] = s * ui + c * aqi;
                }
                // V <- V J (columns)
#pragma unroll
                for (int k = 0; k < 4; ++k) {
                    double apr = Vr[k][p], api = Vi[k][p];
                    double aqr = Vr[k][q], aqi = Vi[k][q];
                    double tr = er * aqr + ei * aqi;
                    double ti = er * aqi - ei * aqr;
                    Vr[k][p] = c * apr - s * tr;
                    Vi[k][p] = c * api - s * ti;
                    double ur = er * apr - ei * api;
                    double ui = er * api + ei * apr;
                    Vr[k][q] = s * ur + c * aqr;
                    Vi[k][q] = s * ui + c * aqi;
                }
            }
    }

    // branchless selection of the 2 smallest eigenvalues (static indexing only)
    double dd[4] = {Ar[0][0], Ar[1][1], Ar[2][2], Ar[3][3]};
    double w[4];
#pragma unroll
    for (int j = 0; j < 4; ++j) {
        int rank = 0;
#pragma unroll
        for (int k = 0; k < 4; ++k) {
            if (k == j) continue;
            bool less = (dd[k] < dd[j]) || (dd[k] == dd[j] && k < j);
            rank += less ? 1 : 0;
        }
        w[j] = (rank < 2) ? 1.0 : 0.0;
    }

#pragma unroll
    for (int m = 0; m < 4; ++m)
#pragma unroll
        for (int n = 0; n < 4; ++n) {
            double rr = 0.0, ii = 0.0;
#pragma unroll
            for (int j = 0; j < 4; ++j) {
                rr += w[j] * (Vr[m][j] * Vr[n][j] + Vi[m][j] * Vi[n][j]);
                ii += w[j] * (Vi[m][j] * Vr[n][j] - Vr[m][j] * Vi[n][j]);
            }
            pre[f * 16 + m * 4 + n] = rr;
            pim[f * 16 + m * 4 + n] = ii;
        }
}

// ---------------------------------------------------------------------------
// Kernel 3: MUSIC spectrum, one block per angle, one thread per frequency.
// ---------------------------------------------------------------------------
__global__ __launch_bounds__(512)
void music_kernel(const double* __restrict__ pre,
                  const double* __restrict__ pim,
                  float* __restrict__ out) {
    int a = blockIdx.x;
    int f = threadIdx.x;
    double r = 0.0;
    if (f < NFREQ) {
        double theta = (-90.0 + 0.5 * (double)a) * PI_D / 180.0;
        double freq = 31.25 * (double)f;
        double phi = 2.0 * PI_D * 0.04 / 343.0 * sin(theta) * freq;
        const double* Pr = pre + f * 16;
        const double* Pi = pim + f * 16;
        double s1, c1;
        sincos(phi, &s1, &c1);
        double c2 = c1 * c1 - s1 * s1;
        double s2 = 2.0 * s1 * c1;
        double c3 = c1 * c2 - s1 * s2;
        double s3 = s1 * c2 + c1 * s2;
        double val = Pr[0] + Pr[5] + Pr[10] + Pr[15]
            + 2.0 * ( c1 * (Pr[1] + Pr[6] + Pr[11]) - s1 * (Pi[1] + Pi[6] + Pi[11])
                    + c2 * (Pr[2] + Pr[7])          - s2 * (Pi[2] + Pi[7])
                    + c3 * Pr[3]                    - s3 * Pi[3] );
        r = 1.0 / (val + 1e-8);
    }
    __shared__ double sm[512];
    sm[threadIdx.x] = r;
    __syncthreads();
    for (int st = 256; st > 0; st >>= 1) {
        if (threadIdx.x < st) sm[threadIdx.x] += sm[threadIdx.x + st];
        __syncthreads();
    }
    if (threadIdx.x == 0) out[a] = (float)(sm[0] / (double)NFREQ);
}

extern "C" void kernel_launch(void* const* d_in, const int* in_sizes, int n_in,
                              void* d_out, int out_size, void* d_ws, size_t ws_size,
                              hipStream_t stream) {
    const float* x = (const float*)d_in[0];
    float* out = (float*)d_out;

    // ws layout:
    //   part_re : 4*4112 floats   (65792 B)
    //   part_im : 4*4112 floats   (65792 B)
    //   pre     : 4112 doubles    (32896 B)
    //   pim     : 4112 doubles    (32896 B)   total 197376 B
    float*  part_re = (float*)d_ws;
    float*  part_im = part_re + 4 * 4112;
    double* pre     = (double*)((char*)d_ws + 2 * 4 * 4112 * sizeof(float));
    double* pim     = pre + 4112;

    stft_kernel<<<64, 512, 0, stream>>>(x, part_re, part_im);
    eig_kernel<<<(NFREQ + 63) / 64, 64, 0, stream>>>(part_re, part_im, pre, pim);
    music_kernel<<<NANG, 512, 0, stream>>>(pre, pim, out);
}

// Round 4
// 110.937 us; speedup vs baseline: 4.4308x; 1.0438x over previous
//
#include <hip/hip_runtime.h>
#include <math.h>

#define NFFT   512
#define HOP    256
#define NFREQ  257
#define NMIC   4
#define NEST   4
#define TSTART 120
#define NANG   361

static constexpr double PI_D = 3.14159265358979323846;
static constexpr float  PI_F = 3.14159265358979323846f;

// ---------------------------------------------------------------------------
// Kernel 1: windowed DFT, fp32 inner loop, 4-way n-chunk split.
// grid = 64 blocks: b = chunk*16 + m*4 + t ; 512 threads (thread = frequency).
// ---------------------------------------------------------------------------
__global__ __launch_bounds__(512)
void stft_kernel(const float* __restrict__ x,
                 float* __restrict__ part_re,
                 float* __restrict__ part_im) {
    int b = blockIdx.x;
    int chunk = b >> 4;
    int m = (b >> 2) & 3;
    int t = b & 3;
    int tid = threadIdx.x;

    __shared__ float ct[512];
    __shared__ float st[512];
    __shared__ float v[128];

    {   // twiddle tables: angle = 2*pi*k/512
        float ang = (2.0f * PI_F / 512.0f) * (float)tid;
        float s, c;
        sincosf(ang, &s, &c);
        ct[tid] = c;
        st[tid] = s;
    }
    if (tid < 128) {
        int n = chunk * 128 + tid;
        long base = ((long)(TSTART + t - 1) * HOP) * NMIC + m;
        v[tid] = x[base + (long)n * NMIC] * sinf(PI_F * (float)n / 512.0f);
    }
    __syncthreads();

    int f = tid;
    if (f >= NFREQ) return;
    int n0 = chunk * 128;
    int k = (f * n0) & 511;
    float re = 0.0f, im = 0.0f;
#pragma unroll 4
    for (int j = 0; j < 128; ++j) {
        float vn = v[j];
        re += vn * ct[k];
        im -= vn * st[k];
        k = (k + f) & 511;
    }
    int id = f * 16 + m * 4 + t;
    part_re[chunk * 4112 + id] = re;
    part_im[chunk * 4112 + id] = im;
}

// ---------------------------------------------------------------------------
// Kernel 2: combine partials -> 4x4 covariance -> complex Jacobi (6 sweeps) ->
// noise projector.
// __launch_bounds__(64, 1): 1 wave/EU -> up to 512 VGPRs so A(32)+V(32)
// doubles stay in registers (round 3: VGPR cap 100 -> scratch-latency-bound).
// Rotation is fully branchless (tiny pivot -> exact identity rotation).
// ---------------------------------------------------------------------------
__global__ __launch_bounds__(64, 1)
void eig_kernel(const float* __restrict__ part_re,
                const float* __restrict__ part_im,
                double* __restrict__ pre,
                double* __restrict__ pim) {
    int f = blockIdx.x * blockDim.x + threadIdx.x;
    if (f >= NFREQ) return;

    double Xr[4][4], Xi[4][4];                     // [m][t]
#pragma unroll
    for (int m = 0; m < 4; ++m)
#pragma unroll
        for (int t = 0; t < 4; ++t) {
            int id = f * 16 + m * 4 + t;
            Xr[m][t] = (double)part_re[id] + (double)part_re[4112 + id]
                     + (double)part_re[2 * 4112 + id] + (double)part_re[3 * 4112 + id];
            Xi[m][t] = (double)part_im[id] + (double)part_im[4112 + id]
                     + (double)part_im[2 * 4112 + id] + (double)part_im[3 * 4112 + id];
        }

    double Ar[4][4], Ai[4][4];
#pragma unroll
    for (int m = 0; m < 4; ++m)
#pragma unroll
        for (int n = 0; n < 4; ++n) {
            double rr = 0.0, ii = 0.0;
#pragma unroll
            for (int t = 0; t < 4; ++t) {
                rr += Xr[m][t] * Xr[n][t] + Xi[m][t] * Xi[n][t];
                ii += Xi[m][t] * Xr[n][t] - Xr[m][t] * Xi[n][t];
            }
            Ar[m][n] = rr;
            Ai[m][n] = ii;
        }

    double Vr[4][4] = {{1,0,0,0},{0,1,0,0},{0,0,1,0},{0,0,0,1}};
    double Vi[4][4] = {{0,0,0,0},{0,0,0,0},{0,0,0,0},{0,0,0,0}};

    for (int sweep = 0; sweep < 6; ++sweep) {
#pragma unroll
        for (int p = 0; p < 3; ++p)
#pragma unroll
            for (int q = p + 1; q < 4; ++q) {
                double ar = Ar[p][q], ai = Ai[p][q];
                double n2 = ar * ar + ai * ai;
                bool ok = n2 > 1e-280;
                double n2s = ok ? n2 : 1.0;          // safe operand, no NaN
                double inv = rsqrt(n2s);             // 1/|a|
                double er = ar * inv, ei = ai * inv; // e^{i alpha} (garbage if !ok, killed by s=0)
                double tau = (Ar[q][q] - Ar[p][p]) * (0.5 * inv * (ok ? 1.0 : 0.0));
                double t_ = (tau >= 0.0 ? 1.0 : -1.0) /
                            (fabs(tau) + sqrt(1.0 + tau * tau));
                double c = ok ? rsqrt(1.0 + t_ * t_) : 1.0;
                double s = ok ? t_ * c : 0.0;
                // A <- A J (columns)
#pragma unroll
                for (int k = 0; k < 4; ++k) {
                    double apr = Ar[k][p], api = Ai[k][p];
                    double aqr = Ar[k][q], aqi = Ai[k][q];
                    double tr = er * aqr + ei * aqi;
                    double ti = er * aqi - ei * aqr;
                    Ar[k][p] = c * apr - s * tr;
                    Ai[k][p] = c * api - s * ti;
                    double ur = er * apr - ei * api;
                    double ui = er * api + ei * apr;
                    Ar[k][q] = s * ur + c * aqr;
                    Ai[k][q] = s * ui + c * aqi;
                }
                // A <- J^H A (rows)
#pragma unroll
                for (int k = 0; k < 4; ++k) {
                    double apr = Ar[p][k], api = Ai[p][k];
                    double aqr = Ar[q][k], aqi = Ai[q][k];
                    double tr = er * aqr - ei * aqi;
                    double ti = er * aqi + ei * aqr;
                    Ar[p][k] = c * apr - s * tr;
                    Ai[p][k] = c * api - s * ti;
                    double ur = er * apr + ei * api;
                    double ui = er * api - ei * apr;
                    Ar[q][k] = s * ur + c * aqr;
                    Ai[q][k] = s * ui + c * aqi;
                }
                // V <- V J (columns)
#pragma unroll
                for (int k = 0; k < 4; ++k) {
                    double apr = Vr[k][p], api = Vi[k][p];
                    double aqr = Vr[k][q], aqi = Vi[k][q];
                    double tr = er * aqr + ei * aqi;
                    double ti = er * aqi - ei * aqr;
                    Vr[k][p] = c * apr - s * tr;
                    Vi[k][p] = c * api - s * ti;
                    double ur = er * apr - ei * api;
                    double ui = er * api + ei * apr;
                    Vr[k][q] = s * ur + c * aqr;
                    Vi[k][q] = s * ui + c * aqi;
                }
            }
    }

    // branchless selection of the 2 smallest eigenvalues (static indexing only)
    double dd[4] = {Ar[0][0], Ar[1][1], Ar[2][2], Ar[3][3]};
    double w[4];
#pragma unroll
    for (int j = 0; j < 4; ++j) {
        int rank = 0;
#pragma unroll
        for (int k = 0; k < 4; ++k) {
            if (k == j) continue;
            bool less = (dd[k] < dd[j]) || (dd[k] == dd[j] && k < j);
            rank += less ? 1 : 0;
        }
        w[j] = (rank < 2) ? 1.0 : 0.0;
    }

#pragma unroll
    for (int m = 0; m < 4; ++m)
#pragma unroll
        for (int n = 0; n < 4; ++n) {
            double rr = 0.0, ii = 0.0;
#pragma unroll
            for (int j = 0; j < 4; ++j) {
                rr += w[j] * (Vr[m][j] * Vr[n][j] + Vi[m][j] * Vi[n][j]);
                ii += w[j] * (Vi[m][j] * Vr[n][j] - Vr[m][j] * Vi[n][j]);
            }
            pre[f * 16 + m * 4 + n] = rr;
            pim[f * 16 + m * 4 + n] = ii;
        }
}

// ---------------------------------------------------------------------------
// Kernel 3: MUSIC spectrum, one block per angle, one thread per frequency.
// ---------------------------------------------------------------------------
__global__ __launch_bounds__(512)
void music_kernel(const double* __restrict__ pre,
                  const double* __restrict__ pim,
                  float* __restrict__ out) {
    int a = blockIdx.x;
    int f = threadIdx.x;
    double r = 0.0;
    if (f < NFREQ) {
        double theta = (-90.0 + 0.5 * (double)a) * PI_D / 180.0;
        double freq = 31.25 * (double)f;
        double phi = 2.0 * PI_D * 0.04 / 343.0 * sin(theta) * freq;
        const double* Pr = pre + f * 16;
        const double* Pi = pim + f * 16;
        double s1, c1;
        sincos(phi, &s1, &c1);
        double c2 = c1 * c1 - s1 * s1;
        double s2 = 2.0 * s1 * c1;
        double c3 = c1 * c2 - s1 * s2;
        double s3 = s1 * c2 + c1 * s2;
        double val = Pr[0] + Pr[5] + Pr[10] + Pr[15]
            + 2.0 * ( c1 * (Pr[1] + Pr[6] + Pr[11]) - s1 * (Pi[1] + Pi[6] + Pi[11])
                    + c2 * (Pr[2] + Pr[7])          - s2 * (Pi[2] + Pi[7])
                    + c3 * Pr[3]                    - s3 * Pi[3] );
        r = 1.0 / (val + 1e-8);
    }
    __shared__ double sm[512];
    sm[threadIdx.x] = r;
    __syncthreads();
    for (int st = 256; st > 0; st >>= 1) {
        if (threadIdx.x < st) sm[threadIdx.x] += sm[threadIdx.x + st];
        __syncthreads();
    }
    if (threadIdx.x == 0) out[a] = (float)(sm[0] / (double)NFREQ);
}

extern "C" void kernel_launch(void* const* d_in, const int* in_sizes, int n_in,
                              void* d_out, int out_size, void* d_ws, size_t ws_size,
                              hipStream_t stream) {
    const float* x = (const float*)d_in[0];
    float* out = (float*)d_out;

    // ws layout:
    //   part_re : 4*4112 floats   (65792 B)
    //   part_im : 4*4112 floats   (65792 B)
    //   pre     : 4112 doubles    (32896 B)
    //   pim     : 4112 doubles    (32896 B)   total 197376 B
    float*  part_re = (float*)d_ws;
    float*  part_im = part_re + 4 * 4112;
    double* pre     = (double*)((char*)d_ws + 2 * 4 * 4112 * sizeof(float));
    double* pim     = pre + 4112;

    stft_kernel<<<64, 512, 0, stream>>>(x, part_re, part_im);
    eig_kernel<<<(NFREQ + 63) / 64, 64, 0, stream>>>(part_re, part_im, pre, pim);
    music_kernel<<<NANG, 512, 0, stream>>>(pre, pim, out);
}

// Round 5
// 108.484 us; speedup vs baseline: 4.5309x; 1.0226x over previous
//
#include <hip/hip_runtime.h>
#include <math.h>

#define NFFT   512
#define HOP    256
#define NFREQ  257
#define NMIC   4
#define TSTART 120
#define NANG   361

static constexpr double PI_D = 3.14159265358979323846;
static constexpr float  PI_F = 3.14159265358979323846f;

// ---------------------------------------------------------------------------
// Kernel 1: windowed DFT, fp32, 4-way n-chunk split.
// grid = 64 blocks: b = chunk*16 + m*4 + t ; 512 threads (thread = frequency).
// float2 twiddle table: one b64 LDS read per tap instead of two b32.
// ---------------------------------------------------------------------------
__global__ __launch_bounds__(512)
void stft_kernel(const float* __restrict__ x,
                 float* __restrict__ part_re,
                 float* __restrict__ part_im) {
    int b = blockIdx.x;
    int chunk = b >> 4;
    int m = (b >> 2) & 3;
    int t = b & 3;
    int tid = threadIdx.x;

    __shared__ float2 tw[512];
    __shared__ float  v[128];

    {   // twiddle: angle = 2*pi*k/512
        float ang = (2.0f * PI_F / 512.0f) * (float)tid;
        float s, c;
        sincosf(ang, &s, &c);
        tw[tid] = make_float2(c, s);
    }
    if (tid < 128) {
        int n = chunk * 128 + tid;
        long base = ((long)(TSTART + t - 1) * HOP) * NMIC + m;
        v[tid] = x[base + (long)n * NMIC] * sinf(PI_F * (float)n / 512.0f);
    }
    __syncthreads();

    int f = tid;
    if (f >= NFREQ) return;
    int k = (f * (chunk * 128)) & 511;
    float re = 0.0f, im = 0.0f;
#pragma unroll 4
    for (int j = 0; j < 128; ++j) {
        float vn = v[j];
        float2 cs = tw[k];
        re += vn * cs.x;
        im -= vn * cs.y;
        k = (k + f) & 511;
    }
    int id = f * 16 + m * 4 + t;
    part_re[chunk * 4112 + id] = re;
    part_im[chunk * 4112 + id] = im;
}

// ---------------------------------------------------------------------------
// Kernel 2: fp32 end-to-end (matches reference's complex64 eigh precision).
// combine partials -> 4x4 covariance -> complex Jacobi (6 sweeps) -> noise
// projector, pre-reduced to the 7 scalars music needs:
//   S1 = P01+P12+P23, S2 = P02+P13, S3 = P03, tr = trace(P).
// State is ~64 VGPRs of fp32 -> cannot spill even at default VGPR budget.
// ---------------------------------------------------------------------------
__global__ __launch_bounds__(64)
void eig_kernel(const float* __restrict__ part_re,
                const float* __restrict__ part_im,
                float* __restrict__ coef) {
    int f = blockIdx.x * blockDim.x + threadIdx.x;
    if (f >= NFREQ) return;

    float Xr[4][4], Xi[4][4];                     // [m][t]
#pragma unroll
    for (int m = 0; m < 4; ++m)
#pragma unroll
        for (int t = 0; t < 4; ++t) {
            int id = f * 16 + m * 4 + t;
            Xr[m][t] = part_re[id] + part_re[4112 + id]
                     + part_re[2 * 4112 + id] + part_re[3 * 4112 + id];
            Xi[m][t] = part_im[id] + part_im[4112 + id]
                     + part_im[2 * 4112 + id] + part_im[3 * 4112 + id];
        }

    float Ar[4][4], Ai[4][4];
#pragma unroll
    for (int m = 0; m < 4; ++m)
#pragma unroll
        for (int n = 0; n < 4; ++n) {
            float rr = 0.0f, ii = 0.0f;
#pragma unroll
            for (int t = 0; t < 4; ++t) {
                rr += Xr[m][t] * Xr[n][t] + Xi[m][t] * Xi[n][t];
                ii += Xi[m][t] * Xr[n][t] - Xr[m][t] * Xi[n][t];
            }
            Ar[m][n] = rr;
            Ai[m][n] = ii;
        }

    float Vr[4][4] = {{1,0,0,0},{0,1,0,0},{0,0,1,0},{0,0,0,1}};
    float Vi[4][4] = {{0,0,0,0},{0,0,0,0},{0,0,0,0},{0,0,0,0}};

    for (int sweep = 0; sweep < 6; ++sweep) {
#pragma unroll
        for (int p = 0; p < 3; ++p)
#pragma unroll
            for (int q = p + 1; q < 4; ++q) {
                float ar = Ar[p][q], ai = Ai[p][q];
                float n2 = ar * ar + ai * ai;
                bool ok = n2 > 1e-24f;
                float n2s = ok ? n2 : 1.0f;
                float inv = 1.0f / sqrtf(n2s);        // 1/|apq|
                float er = ar * inv, ei = ai * inv;   // e^{i alpha}
                float tau = (Ar[q][q] - Ar[p][p]) * (0.5f * inv * (ok ? 1.0f : 0.0f));
                float t_ = (tau >= 0.0f ? 1.0f : -1.0f) /
                           (fabsf(tau) + sqrtf(1.0f + tau * tau));
                float c = ok ? 1.0f / sqrtf(1.0f + t_ * t_) : 1.0f;
                float s = ok ? t_ * c : 0.0f;
                // A <- A J (columns)
#pragma unroll
                for (int k = 0; k < 4; ++k) {
                    float apr = Ar[k][p], api = Ai[k][p];
                    float aqr = Ar[k][q], aqi = Ai[k][q];
                    float tr = er * aqr + ei * aqi;
                    float ti = er * aqi - ei * aqr;
                    Ar[k][p] = c * apr - s * tr;
                    Ai[k][p] = c * api - s * ti;
                    float ur = er * apr - ei * api;
                    float ui = er * api + ei * apr;
                    Ar[k][q] = s * ur + c * aqr;
                    Ai[k][q] = s * ui + c * aqi;
                }
                // A <- J^H A (rows)
#pragma unroll
                for (int k = 0; k < 4; ++k) {
                    float apr = Ar[p][k], api = Ai[p][k];
                    float aqr = Ar[q][k], aqi = Ai[q][k];
                    float tr = er * aqr - ei * aqi;
                    float ti = er * aqi + ei * aqr;
                    Ar[p][k] = c * apr - s * tr;
                    Ai[p][k] = c * api - s * ti;
                    float ur = er * apr + ei * api;
                    float ui = er * api - ei * apr;
                    Ar[q][k] = s * ur + c * aqr;
                    Ai[q][k] = s * ui + c * aqi;
                }
                // V <- V J (columns)
#pragma unroll
                for (int k = 0; k < 4; ++k) {
                    float apr = Vr[k][p], api = Vi[k][p];
                    float aqr = Vr[k][q], aqi = Vi[k][q];
                    float tr = er * aqr + ei * aqi;
                    float ti = er * aqi - ei * aqr;
                    Vr[k][p] = c * apr - s * tr;
                    Vi[k][p] = c * api - s * ti;
                    float ur = er * apr - ei * api;
                    float ui = er * api + ei * apr;
                    Vr[k][q] = s * ur + c * aqr;
                    Vi[k][q] = s * ui + c * aqi;
                }
            }
    }

    // branchless selection of the 2 smallest eigenvalues
    float dd[4] = {Ar[0][0], Ar[1][1], Ar[2][2], Ar[3][3]};
    float w[4];
#pragma unroll
    for (int j = 0; j < 4; ++j) {
        int rank = 0;
#pragma unroll
        for (int k = 0; k < 4; ++k) {
            if (k == j) continue;
            bool less = (dd[k] < dd[j]) || (dd[k] == dd[j] && k < j);
            rank += less ? 1 : 0;
        }
        w[j] = (rank < 2) ? 1.0f : 0.0f;
    }

    // P_mn = sum_j w_j V[m][j] conj(V[n][j]); reduce to what music needs.
    float s1r = 0.f, s1i = 0.f, s2r = 0.f, s2i = 0.f, s3r = 0.f, s3i = 0.f, trc = 0.f;
#pragma unroll
    for (int j = 0; j < 4; ++j) {
        float wj = w[j];
        // (0,1),(1,2),(2,3)
        s1r += wj * (Vr[0][j]*Vr[1][j] + Vi[0][j]*Vi[1][j]
                   + Vr[1][j]*Vr[2][j] + Vi[1][j]*Vi[2][j]
                   + Vr[2][j]*Vr[3][j] + Vi[2][j]*Vi[3][j]);
        s1i += wj * (Vi[0][j]*Vr[1][j] - Vr[0][j]*Vi[1][j]
                   + Vi[1][j]*Vr[2][j] - Vr[1][j]*Vi[2][j]
                   + Vi[2][j]*Vr[3][j] - Vr[2][j]*Vi[3][j]);
        // (0,2),(1,3)
        s2r += wj * (Vr[0][j]*Vr[2][j] + Vi[0][j]*Vi[2][j]
                   + Vr[1][j]*Vr[3][j] + Vi[1][j]*Vi[3][j]);
        s2i += wj * (Vi[0][j]*Vr[2][j] - Vr[0][j]*Vi[2][j]
                   + Vi[1][j]*Vr[3][j] - Vr[1][j]*Vi[3][j]);
        // (0,3)
        s3r += wj * (Vr[0][j]*Vr[3][j] + Vi[0][j]*Vi[3][j]);
        s3i += wj * (Vi[0][j]*Vr[3][j] - Vr[0][j]*Vi[3][j]);
        // trace
        trc += wj * (Vr[0][j]*Vr[0][j] + Vi[0][j]*Vi[0][j]
                   + Vr[1][j]*Vr[1][j] + Vi[1][j]*Vi[1][j]
                   + Vr[2][j]*Vr[2][j] + Vi[2][j]*Vi[2][j]
                   + Vr[3][j]*Vr[3][j] + Vi[3][j]*Vi[3][j]);
    }
    float* cf = coef + f * 8;
    cf[0] = s1r; cf[1] = s1i; cf[2] = s2r; cf[3] = s2i;
    cf[4] = s3r; cf[5] = s3i; cf[6] = trc; cf[7] = 0.0f;
}

// ---------------------------------------------------------------------------
// Kernel 3: MUSIC spectrum. 361 blocks x 320 threads (thread = frequency).
// val = tr + 2*(c1*S1r - s1*S1i + c2*S2r - s2*S2i + c3*S3r - s3*S3i).
// Wave shuffle-reduce + 5 LDS partials (no 9-barrier tree).
// ---------------------------------------------------------------------------
__global__ __launch_bounds__(320)
void music_kernel(const float* __restrict__ coef,
                  float* __restrict__ out) {
    int a = blockIdx.x;
    int tid = threadIdx.x;
    float r = 0.0f;
    if (tid < NFREQ) {
        const float4* cf4 = (const float4*)(coef + tid * 8);
        float4 cA = cf4[0];           // S1r S1i S2r S2i
        float4 cB = cf4[1];           // S3r S3i tr  pad
        float theta = (-90.0f + 0.5f * (float)a) * (PI_F / 180.0f);
        float freq = 31.25f * (float)tid;
        float phi = (float)(2.0 * PI_D * 0.04 / 343.0) * sinf(theta) * freq;
        float s1, c1;
        sincosf(phi, &s1, &c1);
        float c2 = c1 * c1 - s1 * s1;
        float s2 = 2.0f * s1 * c1;
        float c3 = c1 * c2 - s1 * s2;
        float s3 = s1 * c2 + c1 * s2;
        float val = cB.z + 2.0f * (c1 * cA.x - s1 * cA.y
                                 + c2 * cA.z - s2 * cA.w
                                 + c3 * cB.x - s3 * cB.y);
        r = 1.0f / (val + 1e-8f);
    }
#pragma unroll
    for (int off = 32; off > 0; off >>= 1)
        r += __shfl_down(r, off, 64);
    __shared__ float ps[5];
    if ((tid & 63) == 0) ps[tid >> 6] = r;
    __syncthreads();
    if (tid == 0)
        out[a] = (ps[0] + ps[1] + ps[2] + ps[3] + ps[4]) / 257.0f;
}

extern "C" void kernel_launch(void* const* d_in, const int* in_sizes, int n_in,
                              void* d_out, int out_size, void* d_ws, size_t ws_size,
                              hipStream_t stream) {
    const float* x = (const float*)d_in[0];
    float* out = (float*)d_out;

    // ws layout (floats):
    //   part_re : 4*4112           (65792 B)
    //   part_im : 4*4112           (65792 B)
    //   coef    : 257*8            ( 8224 B)   total 139808 B
    float* part_re = (float*)d_ws;
    float* part_im = part_re + 4 * 4112;
    float* coef    = part_im + 4 * 4112;

    stft_kernel<<<64, 512, 0, stream>>>(x, part_re, part_im);
    eig_kernel<<<(NFREQ + 63) / 64, 64, 0, stream>>>(part_re, part_im, coef);
    music_kernel<<<NANG, 320, 0, stream>>>(coef, out);
}